// Round 9
// baseline (702.851 us; speedup 1.0000x reference)
//
#include <hip/hip_runtime.h>
#include <hip/hip_bf16.h>
#include <hip/hip_fp16.h>
#include <cstdint>

// Problem constants (fixed by setup_inputs)
#define N_NODES 102400
#define N_EDGES 1638400
#define N_REL   8
#define D0      256
#define D1      128
#define D2      64

#define WIN     256                 // dsts per coarse bin
#define NBIN    (N_NODES / WIN)     // 400
#define CHA     8192                // edges per partition block
#define NBLKA   (N_EDGES / CHA)     // 200 (exact)

typedef __attribute__((ext_vector_type(8))) short          s16x8;
typedef __attribute__((ext_vector_type(8))) unsigned short u16x8;
typedef __attribute__((ext_vector_type(4))) float          f32x4;

__device__ __forceinline__ unsigned short f2bf(float f) {
    unsigned u = __float_as_uint(f);
    u += 0x7fffu + ((u >> 16) & 1u);           // RNE
    return (unsigned short)(u >> 16);
}
__device__ __forceinline__ float h2f_bits(unsigned short u) {
    __half_raw r; r.x = u;
    return __half2float(__half(r));
}

// ---------------------------------------------------------------------------
__global__ __launch_bounds__(256) void fill0_k(int* __restrict__ p, int total) {
    int i = blockIdx.x * 256 + threadIdx.x;
    if (i < total) p[i] = 0;
}

// Coarse bin counts (bin = dst >> 8), LDS-aggregated
__global__ __launch_bounds__(256) void countA_k(const int* __restrict__ dst,
                                                int* __restrict__ bincnt) {
    __shared__ int h[NBIN];
    const int t  = threadIdx.x;
    const int e0 = blockIdx.x * CHA;
    for (int i = t; i < NBIN; i += 256) h[i] = 0;
    __syncthreads();
#pragma unroll
    for (int i = 0; i < CHA / 256; ++i) {
        int e = e0 + t + i * 256;
        if (e < N_EDGES) atomicAdd(&h[dst[e] >> 8], 1);
    }
    __syncthreads();
    for (int i = t; i < NBIN; i += 256) {
        int c = h[i];
        if (c) atomicAdd(&bincnt[i], c);
    }
}

__device__ __forceinline__ int block_scan_excl_512(int v, int* sA, int* sB, int t) {
    sA[t] = v;
    __syncthreads();
    int* s = sA; int* d = sB;
    for (int o = 1; o < 512; o <<= 1) {
        int x = s[t];
        if (t >= o) x += s[t - o];
        d[t] = x;
        __syncthreads();
        int* tmp = s; s = d; d = tmp;
    }
    return s[t] - v;
}

// Exclusive scan of 400 bin counts (single block)
__global__ __launch_bounds__(512) void scanB_k(const int* __restrict__ bincnt,
                                               int* __restrict__ binbase,
                                               int* __restrict__ bincur) {
    __shared__ int sA[512], sB[512];
    const int t = threadIdx.x;
    int v = (t < NBIN) ? bincnt[t] : 0;
    int excl = block_scan_excl_512(v, sA, sB, t);
    if (t < NBIN) { binbase[t] = excl; bincur[t] = excl; }
    if (t == 0) binbase[NBIN] = N_EDGES;
}

// Partition edges into coarse bins:
//   temp[pos] = { g = et*N + src ,  (half_bits(ew) << 8) | (dst & 255) }
__global__ __launch_bounds__(256) void scatterA_k(const int* __restrict__ src,
                                                  const int* __restrict__ dst,
                                                  const float* __restrict__ ew,
                                                  const int* __restrict__ et,
                                                  int* __restrict__ bincur,
                                                  uint2* __restrict__ temp) {
    __shared__ int h[NBIN];
    const int t  = threadIdx.x;
    const int e0 = blockIdx.x * CHA;
    for (int i = t; i < NBIN; i += 256) h[i] = 0;
    __syncthreads();
#pragma unroll
    for (int i = 0; i < CHA / 256; ++i) {
        int e = e0 + t + i * 256;
        if (e < N_EDGES) atomicAdd(&h[dst[e] >> 8], 1);
    }
    __syncthreads();
    for (int i = t; i < NBIN; i += 256) {
        int c = h[i];
        h[i] = c ? atomicAdd(&bincur[i], c) : 0;
    }
    __syncthreads();
#pragma unroll
    for (int i = 0; i < CHA / 256; ++i) {
        int e = e0 + t + i * 256;
        if (e < N_EDGES) {
            int d   = dst[e];
            int bin = d >> 8;
            unsigned hb = (unsigned)(__half_raw(__float2half(ew[e])).x);
            unsigned g  = (unsigned)(et[e] * N_NODES + src[e]);
            int pos = atomicAdd(&h[bin], 1);
            temp[pos] = make_uint2(g, (hb << 8) | (unsigned)(d & 255));
        }
    }
}

// Per-bin finalize: node-level CSR offsets + dst-sorted edge arrays {eg, ewh}
__global__ __launch_bounds__(512) void passB_k(const uint2* __restrict__ temp,
                                               const int* __restrict__ binbase,
                                               int* __restrict__ off,
                                               unsigned* __restrict__ eg,
                                               unsigned short* __restrict__ ewh) {
    __shared__ int hist[WIN];
    __shared__ int sA[512], sB[512];
    const int b    = blockIdx.x;
    const int t    = threadIdx.x;
    const int beg  = binbase[b], end = binbase[b + 1];
    const int key0 = b * WIN;
    if (t < WIN) hist[t] = 0;
    __syncthreads();
    for (int j = beg + t; j < end; j += 512)
        atomicAdd(&hist[temp[j].y & 255], 1);
    __syncthreads();
    int v = (t < WIN) ? hist[t] : 0;
    int excl = block_scan_excl_512(v, sA, sB, t) + beg;
    if (t < WIN) {
        off[key0 + t] = excl;
        hist[t] = excl;                         // cursor
    }
    __syncthreads();
    for (int j = beg + t; j < end; j += 512) {
        uint2 e = temp[j];
        int pos = atomicAdd(&hist[e.y & 255], 1);
        eg[pos]  = e.x;
        ewh[pos] = (unsigned short)(e.y >> 8);
    }
    if (b == 0 && t == 0) off[N_NODES] = N_EDGES;
}

// ---------------------------------------------------------------------------
// fp32 -> bf16 convert (vectorized float4 -> ushort4)
__global__ __launch_bounds__(256) void cvt_bf16_k(const float* __restrict__ in,
                                                  unsigned short* __restrict__ out,
                                                  int n4) {
    int i = blockIdx.x * 256 + threadIdx.x;
    if (i < n4) {
        float4 v = reinterpret_cast<const float4*>(in)[i];
        ushort4 o;
        o.x = f2bf(v.x); o.y = f2bf(v.y); o.z = f2bf(v.z); o.w = f2bf(v.w);
        reinterpret_cast<ushort4*>(out)[i] = o;
    }
}

// W[R][K][Nn] fp32 -> Wt[R][Nn][K] bf16 (transpose; tiny, launched once)
__global__ __launch_bounds__(256) void cvt_wT_k(const float* __restrict__ in,
                                                unsigned short* __restrict__ out,
                                                int K, int Nn, int total) {
    int o = blockIdx.x * 256 + threadIdx.x;
    if (o < total) {
        int kn = K * Nn;
        int r = o / kn, rem = o % kn;
        int n = rem / K, k = rem % K;
        out[o] = f2bf(in[r * kn + k * Nn + n]);
    }
}

// ---------------------------------------------------------------------------
// bf16 MFMA GEMM, batched over blockIdx.y = relation.
// A is fp32 (converted during LDS staging) when AF32, else bf16. C fp16.
template<int DIN, int DOUT, bool AF32>
__global__ __launch_bounds__(256) void mfma_gemm_b(const void* __restrict__ Av,
                                                   const unsigned short* __restrict__ Bt0,
                                                   __half* __restrict__ C0) {
    constexpr int BM  = 128;
    constexpr int BK  = 64;
    constexpr int BN  = DOUT;
    constexpr int LDK = BK + 8;
    constexpr int FM  = (BM / 2) / 16;          // 4
    constexpr int FN  = (BN / 2) / 16;          // 4 (BN=128) or 2 (BN=64)

    __shared__ __align__(16) unsigned short As[BM][LDK];
    __shared__ __align__(16) unsigned short Bs[BN][LDK];

    const unsigned short* Bt = Bt0 + (size_t)blockIdx.y * DIN * DOUT;
    __half*               C  = C0  + (size_t)blockIdx.y * N_NODES * DOUT;

    const int tid  = threadIdx.x;
    const int wave = tid >> 6;
    const int lane = tid & 63;
    const int lr   = lane & 15;
    const int kq   = lane >> 4;
    const int wm   = (wave >> 1) * (BM / 2);
    const int wn   = (wave & 1) * (BN / 2);
    const int row0 = blockIdx.x * BM;

    f32x4 acc[FM][FN];
#pragma unroll
    for (int i = 0; i < FM; ++i)
#pragma unroll
        for (int j = 0; j < FN; ++j) acc[i][j] = (f32x4){0.f, 0.f, 0.f, 0.f};

    for (int kt = 0; kt < DIN; kt += BK) {
        constexpr int NA = BM * BK / 8;
#pragma unroll
        for (int i = 0; i < NA / 256; ++i) {
            int idx = tid + i * 256;
            int r = idx >> 3;
            int c = (idx & 7) * 8;
            u16x8 v;
            if constexpr (AF32) {
                const float* ap = (const float*)Av + (size_t)(row0 + r) * DIN + kt + c;
                float4 u0 = *reinterpret_cast<const float4*>(ap);
                float4 u1 = *reinterpret_cast<const float4*>(ap + 4);
                v[0] = (short)f2bf(u0.x); v[1] = (short)f2bf(u0.y);
                v[2] = (short)f2bf(u0.z); v[3] = (short)f2bf(u0.w);
                v[4] = (short)f2bf(u1.x); v[5] = (short)f2bf(u1.y);
                v[6] = (short)f2bf(u1.z); v[7] = (short)f2bf(u1.w);
            } else {
                v = *reinterpret_cast<const u16x8*>(
                    (const unsigned short*)Av + (size_t)(row0 + r) * DIN + kt + c);
            }
            *reinterpret_cast<u16x8*>(&As[r][c]) = v;
        }
        constexpr int NB = BN * BK / 8;
#pragma unroll
        for (int i = 0; i < NB / 256; ++i) {
            int idx = tid + i * 256;
            int r = idx >> 3;
            int c = (idx & 7) * 8;
            u16x8 v = *reinterpret_cast<const u16x8*>(&Bt[(size_t)r * DIN + kt + c]);
            *reinterpret_cast<u16x8*>(&Bs[r][c]) = v;
        }
        __syncthreads();

#pragma unroll
        for (int ks = 0; ks < BK; ks += 32) {
            s16x8 af[FM], bfr[FN];
#pragma unroll
            for (int mi = 0; mi < FM; ++mi)
                af[mi] = *reinterpret_cast<const s16x8*>(&As[wm + mi * 16 + lr][ks + kq * 8]);
#pragma unroll
            for (int ni = 0; ni < FN; ++ni)
                bfr[ni] = *reinterpret_cast<const s16x8*>(&Bs[wn + ni * 16 + lr][ks + kq * 8]);
#pragma unroll
            for (int mi = 0; mi < FM; ++mi)
#pragma unroll
                for (int ni = 0; ni < FN; ++ni)
                    acc[mi][ni] = __builtin_amdgcn_mfma_f32_16x16x32_bf16(
                        af[mi], bfr[ni], acc[mi][ni], 0, 0, 0);
        }
        __syncthreads();
    }

#pragma unroll
    for (int mi = 0; mi < FM; ++mi) {
#pragma unroll
        for (int ni = 0; ni < FN; ++ni) {
#pragma unroll
            for (int reg = 0; reg < 4; ++reg) {
                int rrow = row0 + wm + mi * 16 + kq * 4 + reg;
                int ccol = wn + ni * 16 + lr;
                C[(size_t)rrow * DOUT + ccol] = __float2half(acc[mi][ni][reg]);
            }
        }
    }
}

// ---------------------------------------------------------------------------
// Flat CSR gather-reduce over ALL relations at once.
// D1 (=128): TWO waves per node, each owns 64 dims (dim = (wave&1)*64 + lane).
//            Doubles gathers-in-flight per node; same cache-line touches.
// D2 (=64):  one wave per node, lane = dim.
// 4-way unrolled: 4 independent gathers in flight per wave.
// RELUOUT: hb = bf16(relu(bias + acc)); else hf = bias + acc (fp32).
template<int DOUT, bool RELUOUT>
__global__ __launch_bounds__(256) void agg_flat(const int* __restrict__ off,
                                                const unsigned* __restrict__ eg,
                                                const unsigned short* __restrict__ ewh,
                                                const __half* __restrict__ xw,
                                                const float* __restrict__ bias,
                                                float* __restrict__ hf,
                                                unsigned short* __restrict__ hb) {
    const int gwave = (blockIdx.x * 256 + threadIdx.x) >> 6;
    const int lane  = threadIdx.x & 63;

    if (DOUT == 128) {
        const int node = gwave >> 1;
        const int dim  = (gwave & 1) * 64 + lane;
        if (node >= N_NODES) return;
        const int beg = off[node], end = off[node + 1];
        float a = bias[dim];
        int j = beg;
        for (; j + 4 <= end; j += 4) {
            unsigned g0 = eg[j], g1 = eg[j + 1], g2 = eg[j + 2], g3 = eg[j + 3];
            float w0 = h2f_bits(ewh[j]),     w1 = h2f_bits(ewh[j + 1]);
            float w2 = h2f_bits(ewh[j + 2]), w3 = h2f_bits(ewh[j + 3]);
            float f0 = __half2float(xw[(size_t)g0 * 128 + dim]);
            float f1 = __half2float(xw[(size_t)g1 * 128 + dim]);
            float f2 = __half2float(xw[(size_t)g2 * 128 + dim]);
            float f3 = __half2float(xw[(size_t)g3 * 128 + dim]);
            a += w0 * f0 + w1 * f1 + w2 * f2 + w3 * f3;
        }
        for (; j < end; ++j)
            a += h2f_bits(ewh[j]) * __half2float(xw[(size_t)eg[j] * 128 + dim]);
        if (RELUOUT) {
            hb[(size_t)node * 128 + dim] = f2bf(fmaxf(a, 0.f));
        } else {
            hf[(size_t)node * 128 + dim] = a;
        }
    } else {  // DOUT == 64
        const int node = gwave;
        if (node >= N_NODES) return;
        const int beg = off[node], end = off[node + 1];
        float a = bias[lane];
        int j = beg;
        for (; j + 4 <= end; j += 4) {
            unsigned g0 = eg[j], g1 = eg[j + 1], g2 = eg[j + 2], g3 = eg[j + 3];
            float w0 = h2f_bits(ewh[j]),     w1 = h2f_bits(ewh[j + 1]);
            float w2 = h2f_bits(ewh[j + 2]), w3 = h2f_bits(ewh[j + 3]);
            float f0 = __half2float(xw[(size_t)g0 * 64 + lane]);
            float f1 = __half2float(xw[(size_t)g1 * 64 + lane]);
            float f2 = __half2float(xw[(size_t)g2 * 64 + lane]);
            float f3 = __half2float(xw[(size_t)g3 * 64 + lane]);
            a += w0 * f0 + w1 * f1 + w2 * f2 + w3 * f3;
        }
        for (; j < end; ++j)
            a += h2f_bits(ewh[j]) * __half2float(xw[(size_t)eg[j] * 64 + lane]);
        hf[(size_t)node * 64 + lane] = a;
    }
}

// ---------------------------------------------------------------------------
// xw3[r*N + n] = sum_d relu(h2[n,d]) * W3[r,d,0]   ([rel][node] layout!)
__global__ __launch_bounds__(256) void xw3_kernel(const float* __restrict__ h2,
                                                  const float* __restrict__ W3,
                                                  float* __restrict__ xw3) {
    __shared__ float w[D2];
    const int r = blockIdx.y;
    for (int i = threadIdx.x; i < D2; i += 256) w[i] = W3[r * D2 + i];
    __syncthreads();
    int n = blockIdx.x * 256 + threadIdx.x;
    if (n < N_NODES) {
        const float4* hp = reinterpret_cast<const float4*>(h2 + (size_t)n * D2);
        float s = 0.f;
#pragma unroll
        for (int d4 = 0; d4 < D2 / 4; ++d4) {
            float4 v = hp[d4];
            s += fmaxf(v.x, 0.f) * w[d4 * 4]     + fmaxf(v.y, 0.f) * w[d4 * 4 + 1] +
                 fmaxf(v.z, 0.f) * w[d4 * 4 + 2] + fmaxf(v.w, 0.f) * w[d4 * 4 + 3];
        }
        xw3[(size_t)r * N_NODES + n] = s;
    }
}

// Final layer: one thread per dst node, flat edge range, 4-way unroll.
__global__ __launch_bounds__(256) void final_k(const int* __restrict__ off,
                                               const unsigned* __restrict__ eg,
                                               const unsigned short* __restrict__ ewh,
                                               const float* __restrict__ xw3,
                                               const float* __restrict__ b3,
                                               float* __restrict__ out) {
    int d = blockIdx.x * 256 + threadIdx.x;
    if (d >= N_NODES) return;
    float acc = b3[0];
    const int beg = off[d], end = off[d + 1];
    int j = beg;
    for (; j + 4 <= end; j += 4) {
        float w0 = h2f_bits(ewh[j]),     w1 = h2f_bits(ewh[j + 1]);
        float w2 = h2f_bits(ewh[j + 2]), w3 = h2f_bits(ewh[j + 3]);
        float x0 = xw3[eg[j]],     x1 = xw3[eg[j + 1]];
        float x2 = xw3[eg[j + 2]], x3 = xw3[eg[j + 3]];
        acc += w0 * x0 + w1 * x1 + w2 * x2 + w3 * x3;
    }
    for (; j < end; ++j)
        acc += h2f_bits(ewh[j]) * xw3[eg[j]];
    out[d] = acc;
}

// ---------------------------------------------------------------------------
extern "C" void kernel_launch(void* const* d_in, const int* in_sizes, int n_in,
                              void* d_out, int out_size, void* d_ws, size_t ws_size,
                              hipStream_t stream) {
    (void)in_sizes; (void)n_in; (void)out_size;

    const float* z    = (const float*)d_in[0];
    const int*   eidx = (const int*)d_in[1];
    const float* ew   = (const float*)d_in[2];
    const int*   et   = (const int*)d_in[3];
    const float* W1   = (const float*)d_in[4];
    const float* b1   = (const float*)d_in[5];
    const float* W2   = (const float*)d_in[6];
    const float* b2   = (const float*)d_in[7];
    const float* W3   = (const float*)d_in[8];
    const float* b3   = (const float*)d_in[9];

    const int* src = eidx;
    const int* dst = eidx + N_EDGES;

    // ---- adaptive layout: "big" path pre-converts z to bf16 in a 52.4 MB
    //      region shared (time-disjoint) by temp -> z_bf -> h1b ----
    auto pad = [](size_t b) { return (b + 255) & ~(size_t)255; };
    const size_t sz_small  = pad((size_t)N_NODES * D1 * 2);   // 26.2 MB (temp/h1b)
    const size_t sz_big    = pad((size_t)N_NODES * D0 * 2);   // 52.4 MB (+ z_bf)
    const size_t sz_common =
        pad((size_t)(N_NODES + 1) * 4) + pad((size_t)NBIN * 4) +
        pad((size_t)(NBIN + 1) * 4) + pad((size_t)NBIN * 4) +
        pad((size_t)N_EDGES * 4) + pad((size_t)N_EDGES * 2) +
        pad((size_t)N_REL * D0 * D1 * 2) + pad((size_t)N_REL * D1 * D2 * 2) +
        pad((size_t)N_REL * N_NODES * D1 * 2);
    const bool big = ws_size >= sz_common + sz_big + (1u << 20);

    // ---- workspace layout ----
    char* ws = (char*)d_ws;
    size_t o = 0;
    auto alloc = [&](size_t bytes) { char* p = ws + o; o += (bytes + 255) & ~(size_t)255; return p; };
    int*      off     = (int*)     alloc((size_t)(N_NODES + 1) * 4);   // 0.41 MB
    int*      bincnt  = (int*)     alloc((size_t)NBIN * 4);
    int*      binbase = (int*)     alloc((size_t)(NBIN + 1) * 4);
    int*      bincur  = (int*)     alloc((size_t)NBIN * 4);
    unsigned* eg      = (unsigned*)alloc((size_t)N_EDGES * 4);         // 6.55 MB
    unsigned short* ewh = (unsigned short*)alloc((size_t)N_EDGES * 2); // 3.28 MB
    unsigned short* Wt1 = (unsigned short*)alloc((size_t)N_REL * D0 * D1 * 2); // 0.52 MB
    unsigned short* Wt2 = (unsigned short*)alloc((size_t)N_REL * D1 * D2 * 2); // 0.13 MB
    char*     UNION   =            alloc(big ? sz_big : sz_small);     // 52.4 / 26.2 MB
    __half*   xw_all  = (__half*)  alloc((size_t)N_REL * N_NODES * D1 * 2); // 210 MB

    uint2*          temp = (uint2*)UNION;                   // 13.1 MB, dead after passB
    unsigned short* z_bf = (unsigned short*)UNION;          // bf16 z (big path only)
    unsigned short* h1b  = (unsigned short*)UNION;          // bf16 h1, live from L1 agg
    __half*         xw2  = xw_all;                          // L2 xw: [8][N][64] fp16 (105 MB)
    float*          h2f  = (float*)((char*)xw_all + (size_t)N_REL * N_NODES * D2 * 2); // +105 MB
    float*          xw3f = (float*)xw_all;                  // [8][N] f32 (3.3 MB), xw2 dead
    float* out = (float*)d_out;

    // ---- Build dst-sorted edge arrays via two-level binning ----
    fill0_k<<<(NBIN + 255) / 256, 256, 0, stream>>>(bincnt, NBIN);
    countA_k<<<NBLKA, 256, 0, stream>>>(dst, bincnt);
    scanB_k<<<1, 512, 0, stream>>>(bincnt, binbase, bincur);
    scatterA_k<<<NBLKA, 256, 0, stream>>>(src, dst, ew, et, bincur, temp);
    passB_k<<<NBIN, 512, 0, stream>>>(temp, binbase, off, eg, ewh);

    // ---- Weight conversions (bf16, transposed) ----
    cvt_wT_k<<<(N_REL * D0 * D1 + 255) / 256, 256, 0, stream>>>(W1, Wt1, D0, D1, N_REL * D0 * D1);
    cvt_wT_k<<<(N_REL * D1 * D2 + 255) / 256, 256, 0, stream>>>(W2, Wt2, D1, D2, N_REL * D1 * D2);

    // ---- Layer 1: 256 -> 128 (all 8 relations) ----
    if (big) {
        // temp is dead after passB; z_bf reuses its region
        cvt_bf16_k<<<(N_NODES * D0 / 4 + 255) / 256, 256, 0, stream>>>(
            z, z_bf, N_NODES * D0 / 4);
        mfma_gemm_b<D0, D1, false><<<dim3(N_NODES / 128, N_REL), 256, 0, stream>>>(
            z_bf, Wt1, xw_all);
    } else {
        mfma_gemm_b<D0, D1, true><<<dim3(N_NODES / 128, N_REL), 256, 0, stream>>>(
            z, Wt1, xw_all);
    }
    // L1 agg: 2 waves per node (dim-split), 4 waves/block -> N/2 blocks
    agg_flat<D1, true><<<N_NODES / 2, 256, 0, stream>>>(off, eg, ewh, xw_all, b1, nullptr, h1b);

    // ---- Layer 2: 128 -> 64 (A = h1b bf16) ----
    mfma_gemm_b<D1, D2, false><<<dim3(N_NODES / 128, N_REL), 256, 0, stream>>>(
        h1b, Wt2, xw2);
    agg_flat<D2, false><<<N_NODES / 4, 256, 0, stream>>>(off, eg, ewh, xw2, b2, h2f, nullptr);

    // ---- Layer 3: 64 -> 1 ----
    xw3_kernel<<<dim3((N_NODES + 255) / 256, N_REL), 256, 0, stream>>>(h2f, W3, xw3f);
    final_k<<<(N_NODES + 255) / 256, 256, 0, stream>>>(off, eg, ewh, xw3f, b3, out);
}